// Round 1
// baseline (23529.164 us; speedup 1.0000x reference)
//
#include <hip/hip_runtime.h>
#include <math.h>
#include <stdint.h>

#define TB 256    // T time steps
#define NB 32     // batch
#define EV 10000  // vocab
#define ED 256    // embed dim
#define HD 512    // hidden
#define NM 128    // memory slots
#define WDIM 64   // word dim
#define RH 4      // read heads
#define NIF 471   // interface size
#define CEPS 1e-6f

__device__ __forceinline__ float sigm(float x) { return 1.0f / (1.0f + expf(-x)); }
// jax.nn.softplus = logaddexp(x,0), numerically stable form:
__device__ __forceinline__ float sofp(float x) { return fmaxf(x, 0.0f) + log1pf(expf(-fabsf(x))); }

// reductions over values held by threads 0..127; ALL 256 threads must call.
__device__ __forceinline__ float red128_max(float v, int tid, float* red2) {
#pragma unroll
  for (int m = 32; m > 0; m >>= 1) v = fmaxf(v, __shfl_xor(v, m));
  if (tid == 0) red2[0] = v;
  if (tid == 64) red2[1] = v;
  __syncthreads();
  float r = fmaxf(red2[0], red2[1]);
  __syncthreads();
  return r;
}
__device__ __forceinline__ float red128_sum(float v, int tid, float* red2) {
#pragma unroll
  for (int m = 32; m > 0; m >>= 1) v += __shfl_xor(v, m);
  if (tid == 0) red2[0] = v;
  if (tid == 64) red2[1] = v;
  __syncthreads();
  float r = red2[0] + red2[1];
  __syncthreads();
  return r;
}

// ---------------------------------------------------------------- embedding
__global__ __launch_bounds__(256) void k_embed(const int* __restrict__ tok,
                                               const float* __restrict__ emb,
                                               float* __restrict__ x) {
  int gid = blockIdx.x * 256 + threadIdx.x;  // < B*T*E = 2097152
  int bt = gid >> 8, k = gid & 255;
  int t = tok[bt];
  x[gid] = tanhf(emb[(size_t)t * ED + k]);
}

// ------------------------------------------------- LSTM gates + cell update
// Block bk computes units [2*bk, 2*bk+2) x 4 gates for all 32 batches.
// Input vector per batch: [x_t(256) | rv(256) | h_prev(512)], weights
// [w_ih row | w_hh row]. h_prev is read from hrv row (t-1) (or zeroed h0 at
// t=0); h_t is written to hrv row t -> no same-kernel RAW race on h.
__global__ __launch_bounds__(256) void k_gates(
    const float* __restrict__ xall, const float* __restrict__ rv,
    const float* __restrict__ h0, float* __restrict__ c,
    const float* __restrict__ wih, const float* __restrict__ whh,
    const float* __restrict__ blstm, float* __restrict__ hrv, int step) {
  __shared__ float U[NB][257];  // [batch][k-tile], +1 pad -> conflict-free reads
  __shared__ float G[8][NB];
  const int tid = threadIdx.x;
  const int b = tid & 31, jj = tid >> 5;  // jj = ul*4 + g
  const int ul = jj >> 2, g = jj & 3;
  const int u0 = blockIdx.x * 2;
  const int j = (u0 + ul) + (g << 9);  // gate row in [0,2048)
  float acc = blstm[j];
  const float* wbase = wih + (size_t)j * 512;
  const float* wbase2 = whh + (size_t)j * 512;
  for (int tile = 0; tile < 4; ++tile) {
    // cooperative fill of U[bb][0..255] (coalesced: 64 lanes cover one b-row)
#pragma unroll
    for (int i = 0; i < 8; ++i) {
      int f = tid + (i << 8);
      int bb = f >> 6, k = (f & 63) << 2;
      const float* src;
      if (tile == 0)
        src = xall + (((size_t)bb * TB + step) << 8) + k;
      else if (tile == 1)
        src = rv + (bb << 8) + k;
      else {
        const float* hp = step ? (hrv + ((size_t)bb * TB + step - 1) * 768)
                               : (h0 + (bb << 9));
        src = hp + ((tile - 2) << 8) + k;
      }
      float4 v = *reinterpret_cast<const float4*>(src);
      U[bb][k] = v.x; U[bb][k + 1] = v.y; U[bb][k + 2] = v.z; U[bb][k + 3] = v.w;
    }
    __syncthreads();
    const float4* wp = reinterpret_cast<const float4*>(
        (tile < 2 ? wbase : wbase2) + ((tile & 1) << 8));
#pragma unroll 4
    for (int k4 = 0; k4 < 64; ++k4) {
      float4 w4 = wp[k4];
      int k = k4 << 2;
      acc = fmaf(U[b][k], w4.x, acc);
      acc = fmaf(U[b][k + 1], w4.y, acc);
      acc = fmaf(U[b][k + 2], w4.z, acc);
      acc = fmaf(U[b][k + 3], w4.w, acc);
    }
    __syncthreads();
  }
  G[jj][b] = acc;
  __syncthreads();
  if (tid < 64) {
    int u2 = tid >> 5, bb = tid & 31;
    int u = u0 + u2;
    float gi = G[u2 * 4 + 0][bb], gf = G[u2 * 4 + 1][bb];
    float gg = G[u2 * 4 + 2][bb], go = G[u2 * 4 + 3][bb];
    float cold = c[(bb << 9) + u];
    float cn = sigm(gf) * cold + sigm(gi) * tanhf(gg);
    float hn = sigm(go) * tanhf(cn);
    c[(bb << 9) + u] = cn;
    hrv[((size_t)bb * TB + step) * 768 + u] = hn;
  }
}

// --------------------------------------- interface matvec + DNC memory step
// One block per batch. M cached in LDS; L operated in global (L2-resident).
__global__ __launch_bounds__(256) void k_mem(
    float* __restrict__ hrv, const float* __restrict__ wif,
    const float* __restrict__ bif, float* __restrict__ M_g,
    float* __restrict__ L_g, float* __restrict__ p_g, float* __restrict__ u_g,
    float* __restrict__ wr_g, float* __restrict__ ww_g,
    float* __restrict__ rv_g, int step) {
  __shared__ float h_s[512];
  __shared__ float xi_s[472];
  __shared__ float M_s[NM][65];  // +1 pad
  __shared__ float wro_s[4][NM];
  __shared__ float fwd_s[4][NM];
  __shared__ float bwd_s[4][NM];
  __shared__ float crs_s[4][NM];
  __shared__ float wrn_s[4][NM];
  __shared__ float un_s[NM];
  __shared__ float wwn_s[NM];
  __shared__ float po_s[NM];
  __shared__ float er_s[WDIM];
  __shared__ float wv_s[WDIM];
  __shared__ float rb_s[4], fg_s[4], rkn_s[4];
  __shared__ float pi_s[12];
  __shared__ float red2[2];
  __shared__ float sc_s[4];  // 0: wb, 1: ga, 2: gw, 3: |wk|

  const int tid = threadIdx.x;
  const int b = blockIdx.x;
  const size_t row = (size_t)b * TB + step;
  float* hp = hrv + row * 768;
  float* Mg = M_g + (size_t)b * (NM * WDIM);
  float* Lg = L_g + (size_t)b * (NM * NM);

  // ---- phase A: fills
  for (int i = tid; i < 512; i += 256) h_s[i] = hp[i];
  for (int f = tid; f < 2048; f += 256) {
    float4 v = reinterpret_cast<const float4*>(Mg)[f];
    int n = f >> 4, w = (f & 15) << 2;
    M_s[n][w] = v.x; M_s[n][w + 1] = v.y; M_s[n][w + 2] = v.z; M_s[n][w + 3] = v.w;
  }
  for (int i = tid; i < 512; i += 256) wro_s[i >> 7][i & 127] = wr_g[b * 512 + i];
  float uo = 0.f, wwo = 0.f;
  if (tid < 128) {
    uo = u_g[b * 128 + tid];
    wwo = ww_g[b * 128 + tid];
    po_s[tid] = p_g[b * 128 + tid];
  }
  __syncthreads();

  // ---- interface vector: xi = h @ W_iface + b_iface
  for (int cc = tid; cc < NIF; cc += 256) {
    float acc = bif[cc];
#pragma unroll 4
    for (int k = 0; k < 512; ++k) acc = fmaf(h_s[k], wif[(size_t)k * NIF + cc], acc);
    xi_s[cc] = acc;
  }
  __syncthreads();

  // ---- parse interface
  if (tid < 64) {
    er_s[tid] = sigm(xi_s[325 + tid]);
    wv_s[tid] = xi_s[389 + tid];
  } else if (tid < 68) {
    rb_s[tid - 64] = 1.0f + sofp(xi_s[256 + (tid - 64)]);
  } else if (tid < 72) {
    fg_s[tid - 68] = sigm(xi_s[453 + (tid - 68)]);
  } else if (tid < 76) {
    int r = tid - 72;
    float nq = 0.f;
    for (int w = 0; w < 64; ++w) { float v = xi_s[r * 64 + w]; nq = fmaf(v, v, nq); }
    rkn_s[r] = sqrtf(nq);
  } else if (tid < 80) {
    int r = tid - 76;
    float e0 = xi_s[459 + 3 * r], e1 = xi_s[460 + 3 * r], e2 = xi_s[461 + 3 * r];
    float mx = fmaxf(e0, fmaxf(e1, e2));
    float p0 = expf(e0 - mx), p1 = expf(e1 - mx), p2 = expf(e2 - mx);
    float s = p0 + p1 + p2;
    pi_s[3 * r] = p0 / s; pi_s[3 * r + 1] = p1 / s; pi_s[3 * r + 2] = p2 / s;
  } else if (tid == 80) {
    sc_s[0] = 1.0f + sofp(xi_s[324]);
  } else if (tid == 81) {
    sc_s[1] = sigm(xi_s[457]);
  } else if (tid == 82) {
    sc_s[2] = sigm(xi_s[458]);
  } else if (tid == 83) {
    float nq = 0.f;
    for (int w = 0; w < 64; ++w) { float v = xi_s[260 + w]; nq = fmaf(v, v, nq); }
    sc_s[3] = sqrtf(nq);
  }
  __syncthreads();

  // ---- B1: retention/usage + content-write scores (old M)
  float score = -1e30f;
  if (tid < 128) {
    int n = tid;
    float psi = 1.0f;
#pragma unroll
    for (int r = 0; r < 4; ++r) psi *= (1.0f - fg_s[r] * wro_s[r][n]);
    float un = (uo + wwo - uo * wwo) * psi;
    un_s[n] = un;
    u_g[b * 128 + n] = un;
    float dot = 0.f, nq = 0.f;
#pragma unroll 4
    for (int w = 0; w < 64; ++w) {
      float mv = M_s[n][w];
      dot = fmaf(mv, xi_s[260 + w], dot);
      nq = fmaf(mv, mv, nq);
    }
    score = sc_s[0] * dot / (sc_s[3] * sqrtf(nq) + CEPS);
  }
  __syncthreads();

  // ---- B2: allocation (stable-order O(N^2) product == stable argsort+cumprod)
  float aval = 0.f;
  if (tid < 128) {
    int n = tid;
    float un = un_s[n];
    float prod = 1.0f;
#pragma unroll 4
    for (int m = 0; m < 128; ++m) {
      float um = un_s[m];
      bool take = (um < un) || (um == un && m < n);
      prod *= take ? um : 1.0f;
    }
    aval = (1.0f - un) * prod;
  }
  float gmax = red128_max(score, tid, red2);
  float ev = (tid < 128) ? expf(score - gmax) : 0.f;
  float gsum = red128_sum(ev, tid, red2);
  float wwv = 0.f;
  if (tid < 128) {
    float cw = ev / gsum;
    wwv = sc_s[2] * (sc_s[1] * aval + (1.0f - sc_s[1]) * cw);
    wwn_s[tid] = wwv;
    ww_g[b * 128 + tid] = wwv;
  }
  float sumww = red128_sum(wwv, tid, red2);  // syncs make wwn_s visible

  // ---- B3: M update (LDS+global), L update (global), p update
  for (int e = tid; e < NM * WDIM; e += 256) {
    int n = e >> 6, w = e & 63;
    float wn = wwn_s[n];
    float mv = M_s[n][w];
    mv = mv * (1.0f - wn * er_s[w]) + wn * wv_s[w];
    M_s[n][w] = mv;
    Mg[e] = mv;
  }
  for (int e = tid; e < NM * NM; e += 256) {
    int n = e >> 7, m = e & 127;
    float lv = Lg[e];
    float nv = (n == m) ? 0.f
                        : (1.0f - wwn_s[n] - wwn_s[m]) * lv + wwn_s[n] * po_s[m];
    Lg[e] = nv;
  }
  if (tid < 128) p_g[b * 128 + tid] = (1.0f - sumww) * po_s[tid] + wwn_s[tid];
  __syncthreads();

  // ---- B4: fwd/bwd temporal weights (new L, old wr) || cr scores (new M)
  if (tid < 128) {
    int n = tid;
    float f0 = 0, f1 = 0, f2 = 0, f3 = 0, b0 = 0, b1 = 0, b2 = 0, b3 = 0;
#pragma unroll 4
    for (int m = 0; m < 128; ++m) {
      float lnm = Lg[n * 128 + m];
      float lmn = Lg[m * 128 + n];
      float w0 = wro_s[0][m], w1 = wro_s[1][m], w2 = wro_s[2][m], w3 = wro_s[3][m];
      f0 = fmaf(lnm, w0, f0); f1 = fmaf(lnm, w1, f1);
      f2 = fmaf(lnm, w2, f2); f3 = fmaf(lnm, w3, f3);
      b0 = fmaf(lmn, w0, b0); b1 = fmaf(lmn, w1, b1);
      b2 = fmaf(lmn, w2, b2); b3 = fmaf(lmn, w3, b3);
    }
    fwd_s[0][n] = f0; fwd_s[1][n] = f1; fwd_s[2][n] = f2; fwd_s[3][n] = f3;
    bwd_s[0][n] = b0; bwd_s[1][n] = b1; bwd_s[2][n] = b2; bwd_s[3][n] = b3;
  } else {
    int n = tid - 128;
    float d0 = 0, d1 = 0, d2 = 0, d3 = 0, nq = 0;
#pragma unroll 4
    for (int w = 0; w < 64; ++w) {
      float mv = M_s[n][w];
      nq = fmaf(mv, mv, nq);
      d0 = fmaf(mv, xi_s[w], d0);
      d1 = fmaf(mv, xi_s[64 + w], d1);
      d2 = fmaf(mv, xi_s[128 + w], d2);
      d3 = fmaf(mv, xi_s[192 + w], d3);
    }
    float nn = sqrtf(nq);
    crs_s[0][n] = rb_s[0] * d0 / (rkn_s[0] * nn + CEPS);
    crs_s[1][n] = rb_s[1] * d1 / (rkn_s[1] * nn + CEPS);
    crs_s[2][n] = rb_s[2] * d2 / (rkn_s[2] * nn + CEPS);
    crs_s[3][n] = rb_s[3] * d3 / (rkn_s[3] * nn + CEPS);
  }
  __syncthreads();

  // ---- B5: per-head softmax over slots, then read weights
  float crn[4];
  for (int r = 0; r < 4; ++r) {
    float sv = (tid < 128) ? crs_s[r][tid] : -1e30f;
    float gm = red128_max(sv, tid, red2);
    float e2 = (tid < 128) ? expf(sv - gm) : 0.f;
    float gs = red128_sum(e2, tid, red2);
    crn[r] = e2 / gs;
  }
  if (tid < 128) {
    int n = tid;
#pragma unroll
    for (int r = 0; r < 4; ++r) {
      float w = pi_s[3 * r] * bwd_s[r][n] + pi_s[3 * r + 1] * crn[r] +
                pi_s[3 * r + 2] * fwd_s[r][n];
      wrn_s[r][n] = w;
      wr_g[b * 512 + r * 128 + n] = w;
    }
  }
  __syncthreads();

  // ---- B6: read vectors rv = wr_new @ M_new
  {
    int r = tid >> 6, w = tid & 63;
    float acc = 0.f;
#pragma unroll 4
    for (int n = 0; n < 128; ++n) acc = fmaf(wrn_s[r][n], M_s[n][w], acc);
    rv_g[b * 256 + tid] = acc;
    hp[512 + tid] = acc;
  }
}

// ---------------------------------------------- deferred output projection
// C(8192x10000) = A(8192x768) @ W(768x10000) + bias ; fp32, 128x128x8 tiles.
__global__ __launch_bounds__(256) void k_out(const float* __restrict__ A,
                                             const float* __restrict__ W,
                                             const float* __restrict__ bias,
                                             float* __restrict__ C) {
  __shared__ float As[8][128];
  __shared__ float Bs[8][128];
  const int tid = threadIdx.x;
  const int tx = tid & 15, ty = tid >> 4;
  const int m0 = blockIdx.x << 7;
  const int n0 = blockIdx.y << 7;
  float acc[8][8];
#pragma unroll
  for (int i = 0; i < 8; ++i)
#pragma unroll
    for (int j = 0; j < 8; ++j) acc[i][j] = 0.f;
  const int arow = tid >> 1, akk = (tid & 1) << 2;
  const int bk = tid >> 5, bn = (tid & 31) << 2;
  for (int k0 = 0; k0 < 768; k0 += 8) {
    float4 av = *reinterpret_cast<const float4*>(A + (size_t)(m0 + arow) * 768 + k0 + akk);
    float4 bv = make_float4(0.f, 0.f, 0.f, 0.f);
    if (n0 + bn < EV)
      bv = *reinterpret_cast<const float4*>(W + (size_t)(k0 + bk) * EV + n0 + bn);
    __syncthreads();  // previous iteration's reads complete
    As[akk + 0][arow] = av.x; As[akk + 1][arow] = av.y;
    As[akk + 2][arow] = av.z; As[akk + 3][arow] = av.w;
    *reinterpret_cast<float4*>(&Bs[bk][bn]) = bv;
    __syncthreads();
#pragma unroll
    for (int k = 0; k < 8; ++k) {
      float a_[8], b_[8];
#pragma unroll
      for (int i = 0; i < 8; ++i) a_[i] = As[k][ty + (i << 4)];
#pragma unroll
      for (int j = 0; j < 8; ++j) b_[j] = Bs[k][tx + (j << 4)];
#pragma unroll
      for (int i = 0; i < 8; ++i)
#pragma unroll
        for (int j = 0; j < 8; ++j) acc[i][j] = fmaf(a_[i], b_[j], acc[i][j]);
    }
  }
#pragma unroll
  for (int i = 0; i < 8; ++i) {
    int row = m0 + ty + (i << 4);
#pragma unroll
    for (int j = 0; j < 8; ++j) {
      int col = n0 + tx + (j << 4);
      if (col < EV) C[(size_t)row * EV + col] = acc[i][j] + bias[col];
    }
  }
}

extern "C" void kernel_launch(void* const* d_in, const int* in_sizes, int n_in,
                              void* d_out, int out_size, void* d_ws,
                              size_t ws_size, hipStream_t stream) {
  const int* tokens = (const int*)d_in[0];
  const float* emb = (const float*)d_in[1];
  const float* wih = (const float*)d_in[2];
  const float* whh = (const float*)d_in[3];
  const float* blstm = (const float*)d_in[4];
  const float* wif = (const float*)d_in[5];
  const float* bif = (const float*)d_in[6];
  const float* wout = (const float*)d_in[7];
  const float* bout = (const float*)d_in[8];
  float* out = (float*)d_out;

  float* ws = (float*)d_ws;
  float* xall = ws;                    // 2,097,152
  float* hrv = xall + 2097152;         // 6,291,456  (B*T x [h(512)|rv(256)])
  float* h0 = hrv + 6291456;           // state block start (zeroed)
  float* cS = h0 + 16384;
  float* MS = cS + 16384;
  float* LS = MS + 262144;
  float* pS = LS + 524288;
  float* uS = pS + 4096;
  float* wrS = uS + 4096;
  float* wwS = wrS + 16384;
  float* rvS = wwS + 4096;             // ends at h0 + 856064

  hipMemsetAsync(h0, 0, (size_t)856064 * sizeof(float), stream);
  k_embed<<<8192, 256, 0, stream>>>(tokens, emb, xall);
  for (int t = 0; t < TB; ++t) {
    k_gates<<<256, 256, 0, stream>>>(xall, rvS, h0, cS, wih, whh, blstm, hrv, t);
    k_mem<<<32, 256, 0, stream>>>(hrv, wif, bif, MS, LS, pS, uS, wrS, wwS, rvS, t);
  }
  dim3 g(64, 79);
  k_out<<<g, 256, 0, stream>>>(hrv, wout, bout, out);
}